// Round 4
// baseline (322.166 us; speedup 1.0000x reference)
//
#include <hip/hip_runtime.h>
#include <hip/hip_bf16.h>
#include <hip/hip_fp16.h>

#define NN 50000
#define INCH 512
#define OUTCH 64
#define NTILES 3125       // 50000 / 16 (exact)
#define MAXD 48           // ELL slots per row; P(Poisson(16) > 48) ~ 5e-11 per row
#define DEGSTR 16         // deg padded: one counter per 64B cacheline
#define GB 782            // gemm blocks: ceil(3125 tiles / 4 waves)
#define SB 1024           // scatter blocks appended after gemm blocks (128 per XCD)

typedef __attribute__((ext_vector_type(8))) short short8;
typedef __attribute__((ext_vector_type(4))) float floatx4;

__device__ __forceinline__ unsigned packbf2(float a, float b) {
    __hip_bfloat162 h = __float22bfloat162_rn(make_float2(a, b));  // v_cvt_pk_bf16_f32 RNE
    unsigned r;
    __builtin_memcpy(&r, &h, 4);
    return r;
}
__device__ __forceinline__ unsigned short f2bf(float f) {
    unsigned u = __float_as_uint(f);
    return (unsigned short)((u + 0x7FFFu + ((u >> 16) & 1u)) >> 16);  // RNE
}
__device__ __forceinline__ float bf2f(unsigned short u) {
    return __uint_as_float(((unsigned)u) << 16);
}

// ---------------- prep: zero padded deg + convert W fp32 [k][n] -> bf16 [n][k] ----------
__global__ __launch_bounds__(256) void prep_kernel(const float* __restrict__ W,
                                                   unsigned short* __restrict__ Wbf,
                                                   int* __restrict__ deg) {
    const int i = blockIdx.x * 256 + threadIdx.x;
    if (i < (NN * DEGSTR) / 4)
        *reinterpret_cast<uint4*>(deg + i * 4) = uint4{0u, 0u, 0u, 0u};
    if (i < INCH * OUTCH) {
        const int k = i >> 6;          // W is [k][n], read coalesced
        const int n = i & 63;
        Wbf[n * INCH + k] = f2bf(W[i]);
    }
}

// ---------------- fused: [blocks 0..GB) gemm | [GB..GB+SB) partitioned ELL build ------
// gemm: barrier-free 16-row tiles, B from L2-resident global Wbf; epilogue writes
//       QUARTER-MAJOR x0 ([q][row][16ch] bf16) for SpMM gather locality.
// scatter: XCD-exclusive row partitions (r&7 == blockIdx&7 under round-robin
//       dispatch). Each partition's 1.2 MB ELL slice stays L2-resident, so the
//       random 4B RMW stores stop round-tripping to HBM (was 55+54 MB churn).
__global__ __launch_bounds__(256, 4) void fused_gemm_scatter(
        const float* __restrict__ A, const unsigned short* __restrict__ Wbf,
        unsigned short* __restrict__ C,
        const int* __restrict__ rows, const int* __restrict__ cols,
        const float* __restrict__ vals, int* __restrict__ deg,
        unsigned* __restrict__ ell, int E_) {
    __shared__ unsigned short ldsT[4][16 * 64];   // 2 KB per wave, 8 KB total
    const int t = threadIdx.x;

    if (blockIdx.x >= GB) {
        // ---------- partitioned scatter ----------
        const int xcd = blockIdx.x & 7;              // partition this block owns
        const int rank = (blockIdx.x - GB) >> 3;     // dense rank within partition
        for (int e = rank * 256 + t; e < E_; e += (SB / 8) * 256) {
            const int r = rows[e];
            const int c = cols[e];
            const float v = vals[e];
            if ((r & 7) == xcd) {
                const int slot = atomicAdd(&deg[r * DEGSTR], 1);
                const unsigned short hv = __half_as_ushort(__float2half(v));
                if (slot < MAXD)
                    ell[(size_t)r * MAXD + slot] = (unsigned)c | ((unsigned)hv << 16);
            }
        }
        return;
    }

    // ---------- gemm part ----------
    const int lane = t & 63;
    const int wave = t >> 6;
    const int tile = blockIdx.x * 4 + wave;
    if (tile >= NTILES) return;
    const int rbase = tile * 16;
    const int frow = lane & 15;
    const int quad = lane >> 4;
    const float* Ap = A + (size_t)(rbase + frow) * INCH + quad * 8;
    const unsigned short* Bp = Wbf + frow * INCH + quad * 8;

    floatx4 acc[4] = {floatx4{0,0,0,0}, floatx4{0,0,0,0}, floatx4{0,0,0,0}, floatx4{0,0,0,0}};

#pragma unroll
    for (int c = 0; c < 16; ++c) {
        const float4 a0 = *(const float4*)(Ap + c * 32);
        const float4 a1 = *(const float4*)(Ap + c * 32 + 4);
        short8 bfr[4];
#pragma unroll
        for (int f = 0; f < 4; ++f)
            bfr[f] = *(const short8*)(Bp + (size_t)f * 16 * INCH + c * 32);
        uint4 au;
        au.x = packbf2(a0.x, a0.y);
        au.y = packbf2(a0.z, a0.w);
        au.z = packbf2(a1.x, a1.y);
        au.w = packbf2(a1.z, a1.w);
        const short8 af = *(const short8*)&au;
#pragma unroll
        for (int f = 0; f < 4; ++f)
            acc[f] = __builtin_amdgcn_mfma_f32_16x16x32_bf16(af, bfr[f], acc[f], 0, 0, 0);
    }

    // ---------- epilogue: LDS transpose -> QUARTER-MAJOR coalesced stores ----------
    // C/D layout: col = f*16 + frow, row = quad*4 + reg   [m89]
    unsigned short* myT = ldsT[wave];
#pragma unroll
    for (int f = 0; f < 4; ++f)
#pragma unroll
        for (int reg = 0; reg < 4; ++reg)
            myT[(quad * 4 + reg) * 64 + f * 16 + frow] = f2bf(acc[f][reg]);
    // wave-local: ds ordering handled by lgkmcnt, no barrier needed
    // quarter-major: region q holds [row][16ch]; this tile contributes rows
    // rbase..rbase+15 (32B per row per region, 16B-aligned short8 stores).
    {
        const int q = lane >> 4;          // quarter handled by this lane group
        const int sub = lane & 15;        // row within tile
        unsigned short* dst = C + (size_t)q * NN * 16 + (size_t)(rbase + sub) * 16;
        const unsigned short* src = myT + sub * 64 + q * 16;
        *(short8*)dst = *(const short8*)src;
        *(short8*)(dst + 8) = *(const short8*)(src + 8);
    }
}

// ---------------- SpMM over ELL: wave per (row, channel-quarter) ----------
// 16 edge-slots x 4 lanes x 4 channels. All 3 ELL rounds loaded up-front with
// sentinel masking. Quarter-channel split: blockIdx&7 -> XCD; quarter = xcd>>1,
// pair member = xcd&1. Each XCD gathers only from a CONTIGUOUS 1.6 MB
// quarter-major region that fits (with room to spare) in its 4 MB L2, so the
// x16 per-row gather reuse becomes L2 hits. Mapping is a bijection onto
// (quarter, rowgrp) regardless of dispatch order -> correctness never depends
// on the XCD assumption.
template <bool LAST>
__global__ __launch_bounds__(256) void spmm_ell(const int* __restrict__ deg,
                                                const unsigned* __restrict__ ell,
                                                const unsigned short* __restrict__ xin,
                                                void* __restrict__ xout_,
                                                const float* __restrict__ bias) {
    const int b = blockIdx.x;                 // grid = 50000 (6250 * 8)
    const int xcd = b & 7;
    const int q = xcd >> 1;                   // channel quarter: ch [q*16, q*16+16)
    const int p = xcd & 1;                    // pair member
    const int rowgrp = (b >> 3) * 2 + p;      // 0..12499, bijective per quarter
    const int t = threadIdx.x;
    const int lane = t & 63;
    const int eslot = lane >> 2;              // 0..15: edge slot
    const int cg = lane & 3;                  // channel sub-group: 4 ch each
    const int row = rowgrp * 4 + (t >> 6);
    int d = deg[row * DEGSTR];
    d = d < MAXD ? d : MAXD;                  // defensive clamp
    const unsigned* ebase = ell + (size_t)row * MAXD;

    // 3 unconditional slot loads; stale slots beyond d masked by sentinel.
    unsigned p0 = ebase[eslot];
    unsigned p1 = ebase[eslot + 16];
    unsigned p2 = ebase[eslot + 32];
    if (eslot >= d)      p0 = 0u;             // col 0, val 0 -> contributes 0
    if (eslot + 16 >= d) p1 = 0u;
    if (eslot + 32 >= d) p2 = 0u;

    // quarter-major gather base: region q, 4 channels per lane (8B loads)
    const unsigned short* xq = xin + (size_t)q * NN * 16 + cg * 4;
    float a0 = 0.f, a1 = 0.f, a2 = 0.f, a3 = 0.f;

    auto gath = [&](unsigned P) {
        const ushort4 xv = *(const ushort4*)(xq + (size_t)(P & 0xFFFFu) * 16);
        const float v = __half2float(__ushort_as_half((unsigned short)(P >> 16)));
        a0 = fmaf(v, bf2f(xv.x), a0);
        a1 = fmaf(v, bf2f(xv.y), a1);
        a2 = fmaf(v, bf2f(xv.z), a2);
        a3 = fmaf(v, bf2f(xv.w), a3);
    };
    // wave-uniform round skips (d identical across the wave)
    if (d > 0)  gath(p0);
    if (d > 16) gath(p1);
    if (d > 32) gath(p2);

    // reduce across the 16 edge-slots (lane bits 2..5)
    a0 += __shfl_xor(a0, 4, 64);  a1 += __shfl_xor(a1, 4, 64);
    a2 += __shfl_xor(a2, 4, 64);  a3 += __shfl_xor(a3, 4, 64);
    a0 += __shfl_xor(a0, 8, 64);  a1 += __shfl_xor(a1, 8, 64);
    a2 += __shfl_xor(a2, 8, 64);  a3 += __shfl_xor(a3, 8, 64);
    a0 += __shfl_xor(a0, 16, 64); a1 += __shfl_xor(a1, 16, 64);
    a2 += __shfl_xor(a2, 16, 64); a3 += __shfl_xor(a3, 16, 64);
    a0 += __shfl_xor(a0, 32, 64); a1 += __shfl_xor(a1, 32, 64);
    a2 += __shfl_xor(a2, 32, 64); a3 += __shfl_xor(a3, 32, 64);

    if (eslot == 0) {
        if (LAST) {
            // fp32 row-major output: quarter q writes exactly one 64B line/row
            const int chb = q * 16 + cg * 4;
            const float4 bv = *(const float4*)(bias + chb);
            float4 o;
            o.x = a0 + bv.x; o.y = a1 + bv.y; o.z = a2 + bv.z; o.w = a3 + bv.w;
            *(float4*)((float*)xout_ + (size_t)row * OUTCH + chb) = o;
        } else {
            // bf16 quarter-major output (next hop's gather layout); 4 lanes
            // write 32B contiguous; block covers 4 rows = 2 full lines.
            unsigned short* op = (unsigned short*)xout_ + (size_t)q * NN * 16
                               + (size_t)row * 16 + cg * 4;
            ushort4 o;
            o.x = f2bf(a0); o.y = f2bf(a1); o.z = f2bf(a2); o.w = f2bf(a3);
            *(ushort4*)op = o;
        }
    }
}

extern "C" void kernel_launch(void* const* d_in, const int* in_sizes, int n_in,
                              void* d_out, int out_size, void* d_ws, size_t ws_size,
                              hipStream_t stream) {
    const int*   adj   = (const int*)d_in[0];     // [2, E]
    const float* avals = (const float*)d_in[1];   // [E]
    const float* feat  = (const float*)d_in[2];   // [N, 512]
    const float* W     = (const float*)d_in[3];   // [512, 64]
    const float* bias  = (const float*)d_in[4];   // [64]
    float* out = (float*)d_out;

    const int E_ = in_sizes[1];
    const int* rows = adj;
    const int* cols = adj + E_;

    // workspace layout (16B-aligned segments), total ~25.7 MB
    unsigned short* x0  = (unsigned short*)d_ws;            // N*64 bf16 quarter-major (6.4 MB)
    unsigned short* x1  = x0 + (size_t)NN * OUTCH;          // N*64 bf16 quarter-major (6.4 MB)
    unsigned short* Wbf = x1 + (size_t)NN * OUTCH;          // 64*512 bf16 (64 KB)
    unsigned* ell = (unsigned*)(Wbf + (size_t)OUTCH * INCH);// N*MAXD u32 (9.6 MB)
    int* deg = (int*)(ell + (size_t)NN * MAXD);             // N*DEGSTR (3.2 MB)

    // ---- prep: zero padded deg + convert W to bf16 [n][k] ----
    prep_kernel<<<(NN * DEGSTR / 4 + 255) / 256, 256, 0, stream>>>(W, Wbf, deg);

    // ---- fused: dense projection (bf16 MFMA) + partitioned ELL build ----
    fused_gemm_scatter<<<GB + SB, 256, 0, stream>>>(feat, Wbf, x0, rows, cols, avals,
                                                    deg, ell, E_);

    // ---- two SpMM hops; bias fused into the last ----
    spmm_ell<false><<<50000, 256, 0, stream>>>(deg, ell, x0, x1, nullptr);
    spmm_ell<true><<<50000, 256, 0, stream>>>(deg, ell, x1, out, bias);
}

// Round 5
// 288.936 us; speedup vs baseline: 1.1150x; 1.1150x over previous
//
#include <hip/hip_runtime.h>
#include <hip/hip_bf16.h>
#include <hip/hip_fp16.h>

#define NN 50000
#define INCH 512
#define OUTCH 64
#define NTILES 3125       // 50000 / 16 (exact)
#define MAXD 48           // ELL slots per row; P(Poisson(16) > 48) ~ 5e-11 per row
#define GB 782            // gemm blocks: ceil(3125 tiles / 4 waves)
#define SB 512            // scatter blocks appended after gemm blocks

typedef __attribute__((ext_vector_type(8))) short short8;
typedef __attribute__((ext_vector_type(4))) float floatx4;

__device__ __forceinline__ unsigned packbf2(float a, float b) {
    __hip_bfloat162 h = __float22bfloat162_rn(make_float2(a, b));  // v_cvt_pk_bf16_f32 RNE
    unsigned r;
    __builtin_memcpy(&r, &h, 4);
    return r;
}
__device__ __forceinline__ unsigned short f2bf(float f) {
    unsigned u = __float_as_uint(f);
    return (unsigned short)((u + 0x7FFFu + ((u >> 16) & 1u)) >> 16);  // RNE
}
__device__ __forceinline__ float bf2f(unsigned short u) {
    return __uint_as_float(((unsigned)u) << 16);
}

// ---------------- prep: zero deg + convert W fp32 [k][n] -> bf16 [n][k] ----------
__global__ __launch_bounds__(256) void prep_kernel(const float* __restrict__ W,
                                                   unsigned short* __restrict__ Wbf,
                                                   int* __restrict__ deg) {
    const int i = blockIdx.x * 256 + threadIdx.x;
    if (i < NN / 4)   // 12500 uint4 = 50000 ints exactly
        *reinterpret_cast<uint4*>(deg + i * 4) = uint4{0u, 0u, 0u, 0u};
    if (i < INCH * OUTCH) {
        const int k = i >> 6;          // W is [k][n], read coalesced
        const int n = i & 63;
        Wbf[n * INCH + k] = f2bf(W[i]);
    }
}

// ---------------- fused: [blocks 0..GB) gemm | [GB..GB+SB) ELL scatter ----------------
// Streaming accesses (feat, edge list) are NON-TEMPORAL so they stop evicting
// the reusable lines (ELL RMW targets, Wbf) from L2. ELL stores stay normal
// policy: each 64B ELL line receives ~16 scattered 4B stores and we want the
// line to survive in L2 between touches instead of round-tripping to HBM.
__global__ __launch_bounds__(256, 4) void fused_gemm_scatter(
        const float* __restrict__ A, const unsigned short* __restrict__ Wbf,
        unsigned short* __restrict__ C,
        const int* __restrict__ rows, const int* __restrict__ cols,
        const float* __restrict__ vals, int* __restrict__ deg,
        unsigned* __restrict__ ell, int E_) {
    __shared__ unsigned short ldsT[4][16 * 64];   // 2 KB per wave, 8 KB total
    const int t = threadIdx.x;

    if (blockIdx.x >= GB) {
        // ---------- scatter part (single pass, unpadded atomics) ----------
        for (int e = (blockIdx.x - GB) * 256 + t; e < E_; e += SB * 256) {
            const int r = __builtin_nontemporal_load(rows + e);
            const int c = __builtin_nontemporal_load(cols + e);
            const float v = __builtin_nontemporal_load(vals + e);
            const int slot = atomicAdd(&deg[r], 1);
            const unsigned short hv = __half_as_ushort(__float2half(v));
            if (slot < MAXD)
                ell[(size_t)r * MAXD + slot] = (unsigned)c | ((unsigned)hv << 16);
        }
        return;
    }

    // ---------- gemm part ----------
    const int lane = t & 63;
    const int wave = t >> 6;
    const int tile = blockIdx.x * 4 + wave;
    if (tile >= NTILES) return;
    const int rbase = tile * 16;
    const int frow = lane & 15;
    const int quad = lane >> 4;
    const float* Ap = A + (size_t)(rbase + frow) * INCH + quad * 8;
    const unsigned short* Bp = Wbf + frow * INCH + quad * 8;

    floatx4 acc[4] = {floatx4{0,0,0,0}, floatx4{0,0,0,0}, floatx4{0,0,0,0}, floatx4{0,0,0,0}};

#pragma unroll
    for (int c = 0; c < 16; ++c) {
        // feat is single-use streaming: nt load, don't pollute L2
        const floatx4 a0 = __builtin_nontemporal_load((const floatx4*)(Ap + c * 32));
        const floatx4 a1 = __builtin_nontemporal_load((const floatx4*)(Ap + c * 32 + 4));
        short8 bfr[4];
#pragma unroll
        for (int f = 0; f < 4; ++f)   // Wbf is hot: normal cached loads
            bfr[f] = *(const short8*)(Bp + (size_t)f * 16 * INCH + c * 32);
        uint4 au;
        au.x = packbf2(a0[0], a0[1]);
        au.y = packbf2(a0[2], a0[3]);
        au.z = packbf2(a1[0], a1[1]);
        au.w = packbf2(a1[2], a1[3]);
        const short8 af = *(const short8*)&au;
#pragma unroll
        for (int f = 0; f < 4; ++f)
            acc[f] = __builtin_amdgcn_mfma_f32_16x16x32_bf16(af, bfr[f], acc[f], 0, 0, 0);
    }

    // ---------- epilogue: LDS transpose -> row-major coalesced nt stores ----------
    // C/D layout: col = f*16 + frow, row = quad*4 + reg   [m89]
    unsigned short* myT = ldsT[wave];
#pragma unroll
    for (int f = 0; f < 4; ++f)
#pragma unroll
        for (int reg = 0; reg < 4; ++reg)
            myT[(quad * 4 + reg) * 64 + f * 16 + frow] = f2bf(acc[f][reg]);
    // wave-local: ds ordering handled by lgkmcnt, no barrier needed
    unsigned short* Cw = C + (size_t)rbase * OUTCH;
#pragma unroll
    for (int it = 0; it < 2; ++it) {
        const short8 v = *(const short8*)&myT[it * 512 + lane * 8];
        __builtin_nontemporal_store(v, (short8*)(Cw + it * 512 + lane * 8));
    }
}

// ---------------- SpMM over ELL: wave per (row, channel-half) ----------
// 16 edge-slots x 4 lanes x 8 channels. All 3 ELL rounds loaded up-front with
// sentinel masking. Half split (xcd>>2) keeps the per-XCD gather footprint at
// 3.2 MB of whole 64B lines (row-major x: half = exactly one line per row).
// ELL/deg streams and output stores are NON-TEMPORAL so the gather table is
// the only thing competing for L2 -> x16 per-row reuse becomes L2 hits.
// Mapping is bijective regardless of dispatch order -> correctness never
// depends on the XCD assumption.
template <bool LAST>
__global__ __launch_bounds__(256) void spmm_ell(const int* __restrict__ deg,
                                                const unsigned* __restrict__ ell,
                                                const unsigned short* __restrict__ xin,
                                                void* __restrict__ xout_,
                                                const float* __restrict__ bias) {
    const int b = blockIdx.x;                 // grid = 3125 * 8 = 25000
    const int xcd = b & 7;
    const int half = xcd >> 2;                // 0: ch 0-31, 1: ch 32-63
    const int rowgrp = (b >> 3) * 4 + (xcd & 3);   // 0..12499, bijective per half
    const int t = threadIdx.x;
    const int lane = t & 63;
    const int eslot = lane >> 2;              // 0..15: edge slot
    const int cg = lane & 3;                  // channel group: 8 ch each
    const int row = rowgrp * 4 + (t >> 6);
    int d = __builtin_nontemporal_load(deg + row);
    d = d < MAXD ? d : MAXD;                  // defensive clamp
    const unsigned* ebase = ell + (size_t)row * MAXD;

    // 3 unconditional nt slot loads; stale slots beyond d masked by sentinel.
    unsigned p0 = __builtin_nontemporal_load(ebase + eslot);
    unsigned p1 = __builtin_nontemporal_load(ebase + eslot + 16);
    unsigned p2 = __builtin_nontemporal_load(ebase + eslot + 32);
    if (eslot >= d)      p0 = 0u;             // col 0, val 0 -> contributes 0
    if (eslot + 16 >= d) p1 = 0u;
    if (eslot + 32 >= d) p2 = 0u;

    const unsigned short* xh = xin + half * 32 + cg * 8;
    float acc[8] = {0.f, 0.f, 0.f, 0.f, 0.f, 0.f, 0.f, 0.f};

    auto gath = [&](unsigned P) {
        // the gather is the REUSED access: normal cached load
        const short8 xv = *(const short8*)(xh + (size_t)(P & 0xFFFFu) * OUTCH);
        const float v = __half2float(__ushort_as_half((unsigned short)(P >> 16)));
#pragma unroll
        for (int j = 0; j < 8; ++j)
            acc[j] = fmaf(v, bf2f((unsigned short)xv[j]), acc[j]);
    };
    // wave-uniform round skips (d identical across the wave)
    if (d > 0)  gath(p0);
    if (d > 16) gath(p1);
    if (d > 32) gath(p2);

    // reduce across the 16 edge-slots (lane bits 2..5)
#pragma unroll
    for (int j = 0; j < 8; ++j) {
        acc[j] += __shfl_xor(acc[j], 4, 64);
        acc[j] += __shfl_xor(acc[j], 8, 64);
        acc[j] += __shfl_xor(acc[j], 16, 64);
        acc[j] += __shfl_xor(acc[j], 32, 64);
    }

    if (eslot == 0) {
        const int chb = half * 32 + cg * 8;
        if (LAST) {
            float* op = (float*)xout_ + (size_t)row * OUTCH + chb;
            const floatx4 b0 = *(const floatx4*)(bias + chb);
            const floatx4 b1 = *(const floatx4*)(bias + chb + 4);
            floatx4 o0, o1;
            o0[0] = acc[0] + b0[0]; o0[1] = acc[1] + b0[1];
            o0[2] = acc[2] + b0[2]; o0[3] = acc[3] + b0[3];
            o1[0] = acc[4] + b1[0]; o1[1] = acc[5] + b1[1];
            o1[2] = acc[6] + b1[2]; o1[3] = acc[7] + b1[3];
            __builtin_nontemporal_store(o0, (floatx4*)op);
            __builtin_nontemporal_store(o1, (floatx4*)(op + 4));
        } else {
            unsigned short* op = (unsigned short*)xout_ + (size_t)row * OUTCH + chb;
            short8 o;
#pragma unroll
            for (int j = 0; j < 8; ++j) o[j] = (short)f2bf(acc[j]);
            __builtin_nontemporal_store(o, (short8*)op);
        }
    }
}

extern "C" void kernel_launch(void* const* d_in, const int* in_sizes, int n_in,
                              void* d_out, int out_size, void* d_ws, size_t ws_size,
                              hipStream_t stream) {
    const int*   adj   = (const int*)d_in[0];     // [2, E]
    const float* avals = (const float*)d_in[1];   // [E]
    const float* feat  = (const float*)d_in[2];   // [N, 512]
    const float* W     = (const float*)d_in[3];   // [512, 64]
    const float* bias  = (const float*)d_in[4];   // [64]
    float* out = (float*)d_out;

    const int E_ = in_sizes[1];
    const int* rows = adj;
    const int* cols = adj + E_;

    // workspace layout (16B-aligned segments), total ~22.7 MB
    unsigned short* x0  = (unsigned short*)d_ws;            // N*64 bf16 (6.4 MB)
    unsigned short* x1  = x0 + (size_t)NN * OUTCH;          // N*64 bf16 (6.4 MB)
    unsigned short* Wbf = x1 + (size_t)NN * OUTCH;          // 64*512 bf16 (64 KB)
    unsigned* ell = (unsigned*)(Wbf + (size_t)OUTCH * INCH);// N*MAXD u32 (9.6 MB)
    int* deg = (int*)(ell + (size_t)NN * MAXD);             // N int (200 KB)

    // ---- prep: zero deg + convert W to bf16 [n][k] ----
    prep_kernel<<<128, 256, 0, stream>>>(W, Wbf, deg);

    // ---- fused: dense projection (bf16 MFMA) + ELL scatter ----
    fused_gemm_scatter<<<GB + SB, 256, 0, stream>>>(feat, Wbf, x0, rows, cols, avals,
                                                    deg, ell, E_);

    // ---- two SpMM hops; bias fused into the last ----
    spmm_ell<false><<<25000, 256, 0, stream>>>(deg, ell, x0, x1, nullptr);
    spmm_ell<true><<<25000, 256, 0, stream>>>(deg, ell, x1, out, bias);
}